// Round 11
// baseline (151.601 us; speedup 1.0000x reference)
//
#include <hip/hip_runtime.h>
#include <hip/hip_bf16.h>

#define B_ROWS 16384
#define DDIM   512
#define NNODES 1023
#define NLEAF  1024
#define ODIM   256
#define LAMDA  1e-3
#define EPSV   1e-7f

typedef __bf16 bf16x8v __attribute__((ext_vector_type(8)));
typedef _Float16 f16x8 __attribute__((ext_vector_type(8)));
typedef float  f32x16v __attribute__((ext_vector_type(16)));

__device__ __forceinline__ float bf2f(unsigned short u) {
    return __uint_as_float(((unsigned)u) << 16);
}

// async global->LDS 16B copy (dst linear: wave-uniform base + lane*16)
__device__ __forceinline__ void gload16h(const _Float16* g, _Float16* l) {
    __builtin_amdgcn_global_load_lds(
        (const __attribute__((address_space(1))) unsigned int*)g,
        (__attribute__((address_space(3))) unsigned int*)l, 16, 0, 0);
}
__device__ __forceinline__ void gload16b(const __hip_bfloat16* g, __hip_bfloat16* l) {
    __builtin_amdgcn_global_load_lds(
        (const __attribute__((address_space(1))) unsigned int*)g,
        (__attribute__((address_space(3))) unsigned int*)l, 16, 0, 0);
}

// ---------------------------------------------------------------------------
// prep_all: blocks 0..4095 data prep; 4096..4351 W prep; 4352..6403 W copy;
// 6404..7427 softmax_param.  (unchanged from R10)
// ---------------------------------------------------------------------------
__global__ __launch_bounds__(256)
void prep_all(const float* __restrict__ data, const float* __restrict__ W,
              const float* __restrict__ param,
              _Float16* __restrict__ Dh, _Float16* __restrict__ Dl,
              _Float16* __restrict__ Wh, _Float16* __restrict__ Wl,
              float* __restrict__ outW,
              float* __restrict__ logdist, __hip_bfloat16* __restrict__ DT2)
{
    __shared__ float red[4], red2[4];
    if (blockIdx.x < 4096) {
        int idx = blockIdx.x * 256 + threadIdx.x;
        int b  = idx >> 6;
        int k8 = idx & 63;
        const float4 v0 = *reinterpret_cast<const float4*>(&data[(size_t)b * DDIM + k8 * 8]);
        const float4 v1 = *reinterpret_cast<const float4*>(&data[(size_t)b * DDIM + k8 * 8 + 4]);
        float a[8] = {v0.x, v0.y, v0.z, v0.w, v1.x, v1.y, v1.z, v1.w};
        __align__(16) _Float16 h[8], l[8];
#pragma unroll
        for (int j = 0; j < 8; ++j) {
            h[j] = (_Float16)a[j];
            l[j] = (_Float16)((a[j] - (float)h[j]) * 2048.f);
        }
        int by = b >> 8, tl = (b >> 5) & 7, ln = (b & 31) | ((k8 & 1) << 5), ks = k8 >> 1;
        size_t off = ((((size_t)by * 32 + ks) * 8 + tl) * 64 + ln) * 8;
        *reinterpret_cast<ulonglong2*>(&Dh[off]) = *reinterpret_cast<const ulonglong2*>(h);
        *reinterpret_cast<ulonglong2*>(&Dl[off]) = *reinterpret_cast<const ulonglong2*>(l);
    } else if (blockIdx.x < 4352) {
        int idx = (blockIdx.x - 4096) * 256 + threadIdx.x;
        int t  = idx & 255;
        int ks = (idx >> 8) & 31;
        int nb = idx >> 13;
        int tm = t >> 6, ln = t & 63;
        int node = nb * 128 + tm * 32 + (ln & 31);
        int k = ks * 16 + (ln >> 5) * 8;
        __align__(16) _Float16 h[8], l[8];
        if (node < NNODES) {
#pragma unroll
            for (int j = 0; j < 8; ++j) {
                float a = W[(size_t)node * 513 + 1 + k + j];
                h[j] = (_Float16)a;
                l[j] = (_Float16)((a - (float)h[j]) * 2048.f);
            }
        } else {
#pragma unroll
            for (int j = 0; j < 8; ++j) { h[j] = (_Float16)0.f; l[j] = (_Float16)0.f; }
        }
        size_t off = (size_t)idx * 8;
        *reinterpret_cast<ulonglong2*>(&Wh[off]) = *reinterpret_cast<const ulonglong2*>(h);
        *reinterpret_cast<ulonglong2*>(&Wl[off]) = *reinterpret_cast<const ulonglong2*>(l);
    } else if (blockIdx.x < 6404) {
        int i = (blockIdx.x - 4352) * 256 + threadIdx.x;
        if (i < NNODES * 513) outW[i] = W[i];
    } else {
        // softmax over param row l
        int l = blockIdx.x - 6404;
        int o = threadIdx.x;
        float x = param[(size_t)l * ODIM + o];
        float m = x;
#pragma unroll
        for (int s = 1; s < 64; s <<= 1) m = fmaxf(m, __shfl_xor(m, s, 64));
        if ((o & 63) == 0) red[o >> 6] = m;
        __syncthreads();
        m = fmaxf(fmaxf(red[0], red[1]), fmaxf(red[2], red[3]));
        float e = expf(x - m);
        float s = e;
#pragma unroll
        for (int k = 1; k < 64; k <<= 1) s += __shfl_xor(s, k, 64);
        if ((o & 63) == 0) red2[o >> 6] = s;
        __syncthreads();
        s = red2[0] + red2[1] + red2[2] + red2[3];
        float d = e / s;
        logdist[(size_t)l * ODIM + o] = logf(d);
        int kc = l >> 4, kk = l & 15;
        int lane = (o & 31) | ((kk >> 3) << 5);
        DT2[(((size_t)kc * 8 + (o >> 5)) * 64 + lane) * 8 + (kk & 7)] = __float2bfloat16(d);
    }
}

// ---------------------------------------------------------------------------
// GEMM1 fp16-split MFMA  (unchanged from R10: best-so-far 65.4 us)
// tile 128 nodes x 128 batch, 8 waves, per-wave out 64x32, BK=16,
// LDS 2x16KB dbuf, counted vmcnt(2).
// ---------------------------------------------------------------------------
__global__ __launch_bounds__(512, 4)
void gemm1_mfma(const _Float16* __restrict__ Wh, const _Float16* __restrict__ Wl,
                const _Float16* __restrict__ Dh, const _Float16* __restrict__ Dl,
                const float* __restrict__ W, const float* __restrict__ beta,
                float* __restrict__ PT)
{
    __shared__ _Float16 lds[2][8192];
    const int tid = threadIdx.x;
    const int lane = tid & 63;
    const int wv = tid >> 6;
    const int wm = wv & 1, wn = wv >> 1;
    const int id = blockIdx.x;
    const int xcd = id & 7, slot = id >> 3;
    const int bx = slot & 7;
    const int by = xcd * 16 + (slot >> 3);
    const int by256 = by >> 1;
    const int tlb = (by & 1) * 4;

    const int q  = tid & 255;
    const int qt = q >> 6, qn = q & 63;
    const _Float16* Wsel = (tid < 256) ? Wh : Wl;
    const _Float16* Dsel = (tid < 256) ? Dh : Dl;
    const _Float16* wsrc = Wsel + (size_t)bx * 65536 + qt * 512 + qn * 8;
    const _Float16* dsrc = Dsel + (size_t)by256 * 131072 + (tlb + qt) * 512 + qn * 8;

    f32x16v acc_h[2] = {};
    f32x16v acc_l[2] = {};

#define STAGE(buf, ks) do { \
        gload16h(wsrc + (size_t)(ks) * 2048, &lds[buf][tid * 8]); \
        gload16h(dsrc + (size_t)(ks) * 4096, &lds[buf][4096 + tid * 8]); \
    } while (0)

    STAGE(0, 0);
    for (int t = 0; t < 32; ++t) {
        const int cur = t & 1;
        if (t < 31) {
            STAGE(cur ^ 1, t + 1);
            asm volatile("s_waitcnt vmcnt(2)" ::: "memory");
        } else {
            asm volatile("s_waitcnt vmcnt(0)" ::: "memory");
        }
        __builtin_amdgcn_s_barrier();

        f16x8 ah[2], al[2], bh, bl;
#pragma unroll
        for (int i = 0; i < 2; ++i) {
            int ao = ((wm * 2 + i) * 64 + lane) * 8;
            ah[i] = *reinterpret_cast<const f16x8*>(&lds[cur][ao]);
            al[i] = *reinterpret_cast<const f16x8*>(&lds[cur][2048 + ao]);
        }
        {
            int bo = (wn * 64 + lane) * 8;
            bh = *reinterpret_cast<const f16x8*>(&lds[cur][4096 + bo]);
            bl = *reinterpret_cast<const f16x8*>(&lds[cur][6144 + bo]);
        }
        __builtin_amdgcn_s_setprio(1);
#pragma unroll
        for (int i = 0; i < 2; ++i) {
            acc_h[i] = __builtin_amdgcn_mfma_f32_32x32x16_f16(ah[i], bh, acc_h[i], 0, 0, 0);
            acc_l[i] = __builtin_amdgcn_mfma_f32_32x32x16_f16(ah[i], bl, acc_l[i], 0, 0, 0);
            acc_l[i] = __builtin_amdgcn_mfma_f32_32x32x16_f16(al[i], bh, acc_l[i], 0, 0, 0);
        }
        __builtin_amdgcn_s_setprio(0);
        asm volatile("s_waitcnt lgkmcnt(0)" ::: "memory");
        __builtin_amdgcn_s_barrier();
    }
#undef STAGE

#pragma unroll
    for (int i = 0; i < 2; ++i) {
#pragma unroll
        for (int r = 0; r < 16; ++r) {
            int node = bx * 128 + wm * 64 + i * 32 + ((r & 3) + 8 * (r >> 2) + 4 * (lane >> 5));
            if (node < NNODES) {
                float w0 = W[(size_t)node * 513];
                float bt = beta[node];
                float z = acc_h[i][r] + acc_l[i][r] * 4.8828125e-4f;
                float s = bt * (z + w0);
                float p = 1.f / (1.f + expf(-s));
                PT[(size_t)node * B_ROWS + by * 128 + wn * 32 + (lane & 31)] = p;
            }
        }
    }
}

// ---------------------------------------------------------------------------
// Tree pass + fused colsum: thread = row, one subtree-pair per block.
// Writes fragment-tiled MU2, per-pair partial argmax (pval/pidx), and
// block-level leaf column-sums via LDS transpose -> atomicAdd leafsum[1024].
// ---------------------------------------------------------------------------
__global__ __launch_bounds__(256, 4)
void tree_pass(const float* __restrict__ PT,
               __hip_bfloat16* __restrict__ MU2,
               float* __restrict__ pval,          // [16][16384]
               int*   __restrict__ pidx,          // [16][16384]
               float* __restrict__ leafsum)       // [1024], pre-zeroed
{
    __shared__ float cs[32][257];      // 32.1 KB transpose buffer
    __shared__ float ps[32][8];
    const int tid = threadIdx.x;
    const int rb = blockIdx.x & 63;
    const int g  = blockIdx.x >> 6;        // pair 0..15
    const int b  = rb * 256 + tid;

    const int c4 = 15 + g;
    const int n3 = (c4 - 1) >> 1;
    const int n2 = (n3 - 1) >> 1;
    const int n1 = (n2 - 1) >> 1;
    const float pc4 = PT[(size_t)c4 * B_ROWS + b];
    const float pn3 = PT[(size_t)n3 * B_ROWS + b];
    const float pn2 = PT[(size_t)n2 * B_ROWS + b];
    const float pn1 = PT[(size_t)n1 * B_ROWS + b];
    const float pn0 = PT[b];
    float pre = ((c4 & 1) ? pn3 : 1.f - pn3)
              * ((n3 & 1) ? pn2 : 1.f - pn2)
              * ((n2 & 1) ? pn1 : 1.f - pn1)
              * ((n1 & 1) ? pn0 : 1.f - pn0);
    float root[2] = { pre * pc4, pre * (1.f - pc4) };

    __align__(16) __hip_bfloat16 mbv[64];
    float bestv = -1.f; int besti = 0;
#pragma unroll
    for (int ss = 0; ss < 2; ++ss) {
        const int t = 2 * g + ss;
        float s[32];
#pragma unroll
        for (int u = 1; u < 32; ++u) {
            int lvl = 31 - __clz(u);
            int node = ((32 << lvl) - 1) + t * (1 << lvl) + (u - (1 << lvl));
            s[u] = PT[(size_t)node * B_ROWS + b];
        }
        float w[64];
        w[1] = root[ss];
#pragma unroll
        for (int u = 1; u < 32; ++u) {
            w[2 * u]     = w[u] * s[u];
            w[2 * u + 1] = w[u] * (1.f - s[u]);
        }
#pragma unroll
        for (int q = 0; q < 32; ++q) {
            float lv = w[32 + q];
            mbv[ss * 32 + q] = __float2bfloat16(lv);
            if (lv > bestv) { bestv = lv; besti = t * 32 + q; }
        }
        // ---- fused colsum: LDS transpose reduce over the block's 256 rows ----
#pragma unroll
        for (int q = 0; q < 32; ++q) cs[q][tid] = w[32 + q];   // conflict-free
        __syncthreads();
        {
            const int q = tid & 31, seg = tid >> 5;            // 8 segs x 32 rows
            float sum = 0.f;
#pragma unroll
            for (int r = 0; r < 32; ++r) sum += cs[q][seg * 32 + r];
            ps[q][seg] = sum;
        }
        __syncthreads();
        if (tid < 32) {
            float tot = 0.f;
#pragma unroll
            for (int sg = 0; sg < 8; ++sg) tot += ps[tid][sg];
            atomicAdd(&leafsum[t * 32 + tid], tot);
        }
        __syncthreads();                                       // protect cs reuse
    }
    // scatter into fragment-tiled MU2: 8x 16B coalesced stores
    {
        const int mb_ = b >> 7, mt_ = (b >> 5) & 3, lnlo = b & 31;
        const ulonglong2* src = reinterpret_cast<const ulonglong2*>(mbv);
#pragma unroll
        for (int c = 0; c < 4; ++c) {
            size_t base16 = (((size_t)mb_ * 64 + g * 4 + c) * 4 + mt_) * 64;
            *reinterpret_cast<ulonglong2*>(&MU2[(base16 + lnlo) * 8])      = src[c * 2];
            *reinterpret_cast<ulonglong2*>(&MU2[(base16 + 32 + lnlo) * 8]) = src[c * 2 + 1];
        }
    }
    pval[(size_t)g * B_ROWS + b] = bestv;
    pidx[(size_t)g * B_ROWS + b] = besti;
}

// ---------------------------------------------------------------------------
// finalize: blocks 0..255 = argmax over 16 partials + gather logdist rows;
// block 256 = penalty from leafsum.
// ---------------------------------------------------------------------------
__global__ __launch_bounds__(256)
void finalize(const float* __restrict__ pval, const int* __restrict__ pidx,
              const float* __restrict__ logdist, float* __restrict__ out0,
              const float* __restrict__ leafsum, float* __restrict__ out_pen)
{
    __shared__ int sid[64];
    __shared__ float M[2048];
    __shared__ double dred[256];
    const int t = threadIdx.x;
    if (blockIdx.x == 256) {
        // ---- penalty ----
        for (int i = t; i < 1024; i += 256) M[1024 + i] = leafsum[i];
        __syncthreads();
        for (int n = 512; n >= 1; n >>= 1) {
            for (int u = n + t; u < 2 * n; u += 256) M[u] = M[2 * u] + M[2 * u + 1];
            __syncthreads();
        }
        double acc = 0.0;
        for (int u = 2 + t; u < 2048; u += 256) {
            int lvl = 31 - __clz(u);
            float a = M[u] / (M[u >> 1] + EPSV);
            a = fminf(fmaxf(a, EPSV), 1.f - EPSV);
            float term = logf(a) + logf(1.f - a);
            acc -= ldexp((double)LAMDA * 0.5, 1 - lvl) * (double)term;
        }
        dred[t] = acc;
        __syncthreads();
        for (int s = 128; s > 0; s >>= 1) {
            if (t < s) dred[t] += dred[t + s];
            __syncthreads();
        }
        if (t == 0) out_pen[0] = (float)dred[0];
        return;
    }
    const int blk = blockIdx.x;           // 256 blocks x 64 rows
    if (t < 64) {
        int row = blk * 64 + t;
        float bv = -1.f; int bi = 0;
        for (int g = 0; g < 16; ++g) {
            float v = pval[(size_t)g * B_ROWS + row];
            if (v > bv) { bv = v; bi = pidx[(size_t)g * B_ROWS + row]; }
        }
        sid[t] = bi;
    }
    __syncthreads();
    for (int rr = 0; rr < 64; ++rr) {
        int id = sid[rr];
        out0[(size_t)(blk * 64 + rr) * ODIM + t] = logdist[(size_t)id * ODIM + t];
    }
}

// ---------------------------------------------------------------------------
// GEMM2: out1 = log(MU2 @ DT2), M-tile 64, N=256, BK=32, dbuf gload_lds.
// ---------------------------------------------------------------------------
__global__ __launch_bounds__(256)
void gemm2_log(const __hip_bfloat16* __restrict__ MU2,
               const __hip_bfloat16* __restrict__ DT2,
               float* __restrict__ out1)
{
    __shared__ __hip_bfloat16 ldsA[2][2048];
    __shared__ __hip_bfloat16 ldsB[2][8192];
    const int tid = threadIdx.x;
    const int lane = tid & 63;
    const int w = tid >> 6;
    const int blk = blockIdx.x;
    const int m0 = blk * 64;
    const int mb = blk >> 1;
    const int mtbase = (blk & 1) * 2;
    const int s_kcl = tid >> 7, s_mti = (tid >> 6) & 1, s_ln = tid & 63;

    f32x16v acc[2][2] = {};

#define STAGE2(buf, kc0) do { \
        size_t sa16 = (((size_t)mb * 64 + (kc0) + s_kcl) * 4 + mtbase + s_mti) * 64 + s_ln; \
        gload16b(MU2 + sa16 * 8, &ldsA[buf][tid * 8]); \
        gload16b(DT2 + ((size_t)(kc0) * 512 + tid) * 8,             &ldsB[buf][tid * 8]); \
        gload16b(DT2 + ((size_t)(kc0) * 512 + 256 + tid) * 8,       &ldsB[buf][2048 + tid * 8]); \
        gload16b(DT2 + ((size_t)((kc0) + 1) * 512 + tid) * 8,       &ldsB[buf][4096 + tid * 8]); \
        gload16b(DT2 + ((size_t)((kc0) + 1) * 512 + 256 + tid) * 8, &ldsB[buf][6144 + tid * 8]); \
    } while (0)

    STAGE2(0, 0);
    for (int it = 0; it < 32; ++it) {
        const int cur = it & 1;
        if (it + 1 < 32) {
            STAGE2(cur ^ 1, 2 * (it + 1));
            asm volatile("s_waitcnt vmcnt(5)" ::: "memory");
        } else {
            asm volatile("s_waitcnt vmcnt(0)" ::: "memory");
        }
        __builtin_amdgcn_s_barrier();
        bf16x8v a[2][2], bb[2][2];
#pragma unroll
        for (int kcl = 0; kcl < 2; ++kcl)
#pragma unroll
            for (int i = 0; i < 2; ++i) {
                a[kcl][i]  = *reinterpret_cast<const bf16x8v*>(&ldsA[cur][((kcl * 2 + i) * 64 + lane) * 8]);
                bb[kcl][i] = *reinterpret_cast<const bf16x8v*>(&ldsB[cur][((kcl * 8 + 2 * w + i) * 64 + lane) * 8]);
            }
        __builtin_amdgcn_s_setprio(1);
#pragma unroll
        for (int kcl = 0; kcl < 2; ++kcl)
#pragma unroll
            for (int i = 0; i < 2; ++i)
#pragma unroll
                for (int j = 0; j < 2; ++j)
                    acc[i][j] = __builtin_amdgcn_mfma_f32_32x32x16_bf16(a[kcl][i], bb[kcl][j], acc[i][j], 0, 0, 0);
        __builtin_amdgcn_s_setprio(0);
        asm volatile("s_waitcnt lgkmcnt(0)" ::: "memory");
        __builtin_amdgcn_s_barrier();
    }
#undef STAGE2
#pragma unroll
    for (int i = 0; i < 2; ++i)
#pragma unroll
        for (int j = 0; j < 2; ++j)
#pragma unroll
            for (int r = 0; r < 16; ++r) {
                int row = m0 + i * 32 + (r & 3) + 8 * (r >> 2) + 4 * (lane >> 5);
                int col = w * 64 + j * 32 + (lane & 31);
                out1[(size_t)row * ODIM + col] = logf(acc[i][j][r]);
            }
}

// ---------------------------------------------------------------------------
extern "C" void kernel_launch(void* const* d_in, const int* in_sizes, int n_in,
                              void* d_out, int out_size, void* d_ws, size_t ws_size,
                              hipStream_t stream)
{
    (void)in_sizes; (void)n_in; (void)out_size; (void)ws_size;
    const float* data  = (const float*)d_in[0];
    const float* W     = (const float*)d_in[1];
    const float* beta  = (const float*)d_in[2];
    const float* param = (const float*)d_in[3];
    float* out = (float*)d_out;

    char* ws = (char*)d_ws;
    size_t off = 0;
    float* PT = (float*)(ws + off);                   off += (size_t)NNODES * B_ROWS * 4;   // 67.04 MB
    char* X = ws + off;                               off += 2 * 1048576 + 2 * 16777216;    // 35.65 MB
    _Float16* Wh = (_Float16*)(X);
    _Float16* Wl = (_Float16*)(X + 1048576);
    _Float16* Dh = (_Float16*)(X + 2 * 1048576);
    _Float16* Dl = (_Float16*)(X + 2 * 1048576 + 16777216);
    __hip_bfloat16* MU2 = (__hip_bfloat16*)(X + 2 * 1048576);  // overlays Dh+Dl (33.55 MB)
    __hip_bfloat16* DT2 = (__hip_bfloat16*)(ws + off); off += (size_t)ODIM * NLEAF * 2;
    float* logdist = (float*)(ws + off);              off += (size_t)NLEAF * ODIM * 4;
    float* leafsum = (float*)(ws + off);              off += (size_t)NLEAF * 4;
    float* pval    = (float*)(ws + off);              off += (size_t)16 * B_ROWS * 4;
    int*   pidx    = (int*)(ws + off);                off += (size_t)16 * B_ROWS * 4;

    float* out_logpred = out;
    float* out_logout  = out + (size_t)B_ROWS * ODIM;
    float* out_pen     = out + 2 * (size_t)B_ROWS * ODIM;
    float* out_W       = out_pen + 1;

    hipMemsetAsync(leafsum, 0, NLEAF * 4, stream);
    prep_all<<<7428, 256, 0, stream>>>(data, W, param, Dh, Dl, Wh, Wl, out_W, logdist, DT2);

    gemm1_mfma<<<1024, 512, 0, stream>>>(Wh, Wl, Dh, Dl, W, beta, PT);

    tree_pass<<<1024, 256, 0, stream>>>(PT, MU2, pval, pidx, leafsum);

    gemm2_log<<<256, 256, 0, stream>>>(MU2, DT2, out_logout);

    finalize<<<257, 256, 0, stream>>>(pval, pidx, logdist, out_logpred, leafsum, out_pen);
}

// Round 12
// 137.538 us; speedup vs baseline: 1.1022x; 1.1022x over previous
//
#include <hip/hip_runtime.h>
#include <hip/hip_bf16.h>

#define B_ROWS 16384
#define DDIM   512
#define NNODES 1023
#define NLEAF  1024
#define ODIM   256
#define LAMDA  1e-3
#define EPSV   1e-7f

typedef __bf16 bf16x8v __attribute__((ext_vector_type(8)));
typedef _Float16 f16x8 __attribute__((ext_vector_type(8)));
typedef float  f32x16v __attribute__((ext_vector_type(16)));

__device__ __forceinline__ float bf2f(unsigned short u) {
    return __uint_as_float(((unsigned)u) << 16);
}

// async global->LDS 16B copy (dst linear: wave-uniform base + lane*16)
__device__ __forceinline__ void gload16h(const _Float16* g, _Float16* l) {
    __builtin_amdgcn_global_load_lds(
        (const __attribute__((address_space(1))) unsigned int*)g,
        (__attribute__((address_space(3))) unsigned int*)l, 16, 0, 0);
}
__device__ __forceinline__ void gload16b(const __hip_bfloat16* g, __hip_bfloat16* l) {
    __builtin_amdgcn_global_load_lds(
        (const __attribute__((address_space(1))) unsigned int*)g,
        (__attribute__((address_space(3))) unsigned int*)l, 16, 0, 0);
}

// ---------------------------------------------------------------------------
// prep_all: blocks 0..4095 data prep; 4096..4351 W prep; 4352..6403 W copy;
// 6404..7427 softmax_param; 7428 leafsum zero.
// ---------------------------------------------------------------------------
__global__ __launch_bounds__(256)
void prep_all(const float* __restrict__ data, const float* __restrict__ W,
              const float* __restrict__ param,
              _Float16* __restrict__ Dh, _Float16* __restrict__ Dl,
              _Float16* __restrict__ Wh, _Float16* __restrict__ Wl,
              float* __restrict__ outW,
              float* __restrict__ logdist, __hip_bfloat16* __restrict__ DT2,
              float* __restrict__ leafsum)
{
    __shared__ float red[4], red2[4];
    if (blockIdx.x < 4096) {
        int idx = blockIdx.x * 256 + threadIdx.x;
        int b  = idx >> 6;
        int k8 = idx & 63;
        const float4 v0 = *reinterpret_cast<const float4*>(&data[(size_t)b * DDIM + k8 * 8]);
        const float4 v1 = *reinterpret_cast<const float4*>(&data[(size_t)b * DDIM + k8 * 8 + 4]);
        float a[8] = {v0.x, v0.y, v0.z, v0.w, v1.x, v1.y, v1.z, v1.w};
        __align__(16) _Float16 h[8], l[8];
#pragma unroll
        for (int j = 0; j < 8; ++j) {
            h[j] = (_Float16)a[j];
            l[j] = (_Float16)((a[j] - (float)h[j]) * 2048.f);
        }
        int by = b >> 8, tl = (b >> 5) & 7, ln = (b & 31) | ((k8 & 1) << 5), ks = k8 >> 1;
        size_t off = ((((size_t)by * 32 + ks) * 8 + tl) * 64 + ln) * 8;
        *reinterpret_cast<ulonglong2*>(&Dh[off]) = *reinterpret_cast<const ulonglong2*>(h);
        *reinterpret_cast<ulonglong2*>(&Dl[off]) = *reinterpret_cast<const ulonglong2*>(l);
    } else if (blockIdx.x < 4352) {
        int idx = (blockIdx.x - 4096) * 256 + threadIdx.x;
        int t  = idx & 255;
        int ks = (idx >> 8) & 31;
        int nb = idx >> 13;
        int tm = t >> 6, ln = t & 63;
        int node = nb * 128 + tm * 32 + (ln & 31);
        int k = ks * 16 + (ln >> 5) * 8;
        __align__(16) _Float16 h[8], l[8];
        if (node < NNODES) {
#pragma unroll
            for (int j = 0; j < 8; ++j) {
                float a = W[(size_t)node * 513 + 1 + k + j];
                h[j] = (_Float16)a;
                l[j] = (_Float16)((a - (float)h[j]) * 2048.f);
            }
        } else {
#pragma unroll
            for (int j = 0; j < 8; ++j) { h[j] = (_Float16)0.f; l[j] = (_Float16)0.f; }
        }
        size_t off = (size_t)idx * 8;
        *reinterpret_cast<ulonglong2*>(&Wh[off]) = *reinterpret_cast<const ulonglong2*>(h);
        *reinterpret_cast<ulonglong2*>(&Wl[off]) = *reinterpret_cast<const ulonglong2*>(l);
    } else if (blockIdx.x < 6404) {
        int i = (blockIdx.x - 4352) * 256 + threadIdx.x;
        if (i < NNODES * 513) outW[i] = W[i];
    } else if (blockIdx.x < 7428) {
        // softmax over param row l
        int l = blockIdx.x - 6404;
        int o = threadIdx.x;
        float x = param[(size_t)l * ODIM + o];
        float m = x;
#pragma unroll
        for (int s = 1; s < 64; s <<= 1) m = fmaxf(m, __shfl_xor(m, s, 64));
        if ((o & 63) == 0) red[o >> 6] = m;
        __syncthreads();
        m = fmaxf(fmaxf(red[0], red[1]), fmaxf(red[2], red[3]));
        float e = expf(x - m);
        float s = e;
#pragma unroll
        for (int k = 1; k < 64; k <<= 1) s += __shfl_xor(s, k, 64);
        if ((o & 63) == 0) red2[o >> 6] = s;
        __syncthreads();
        s = red2[0] + red2[1] + red2[2] + red2[3];
        float d = e / s;
        logdist[(size_t)l * ODIM + o] = logf(d);
        int kc = l >> 4, kk = l & 15;
        int lane = (o & 31) | ((kk >> 3) << 5);
        DT2[(((size_t)kc * 8 + (o >> 5)) * 64 + lane) * 8 + (kk & 7)] = __float2bfloat16(d);
    } else {
        // zero leafsum
        float4 z = {0.f, 0.f, 0.f, 0.f};
        *reinterpret_cast<float4*>(&leafsum[threadIdx.x * 4]) = z;
    }
}

// ---------------------------------------------------------------------------
// GEMM1 fp16-split MFMA  (frozen at best-so-far 65.3 us / MfmaUtil ~33%)
// tile 128 nodes x 128 batch, 8 waves, per-wave out 64x32, BK=16,
// LDS 2x16KB dbuf, counted vmcnt(2).
// ---------------------------------------------------------------------------
__global__ __launch_bounds__(512, 4)
void gemm1_mfma(const _Float16* __restrict__ Wh, const _Float16* __restrict__ Wl,
                const _Float16* __restrict__ Dh, const _Float16* __restrict__ Dl,
                const float* __restrict__ W, const float* __restrict__ beta,
                float* __restrict__ PT)
{
    __shared__ _Float16 lds[2][8192];
    const int tid = threadIdx.x;
    const int lane = tid & 63;
    const int wv = tid >> 6;
    const int wm = wv & 1, wn = wv >> 1;
    const int id = blockIdx.x;
    const int xcd = id & 7, slot = id >> 3;
    const int bx = slot & 7;
    const int by = xcd * 16 + (slot >> 3);
    const int by256 = by >> 1;
    const int tlb = (by & 1) * 4;

    const int q  = tid & 255;
    const int qt = q >> 6, qn = q & 63;
    const _Float16* Wsel = (tid < 256) ? Wh : Wl;
    const _Float16* Dsel = (tid < 256) ? Dh : Dl;
    const _Float16* wsrc = Wsel + (size_t)bx * 65536 + qt * 512 + qn * 8;
    const _Float16* dsrc = Dsel + (size_t)by256 * 131072 + (tlb + qt) * 512 + qn * 8;

    f32x16v acc_h[2] = {};
    f32x16v acc_l[2] = {};

#define STAGE(buf, ks) do { \
        gload16h(wsrc + (size_t)(ks) * 2048, &lds[buf][tid * 8]); \
        gload16h(dsrc + (size_t)(ks) * 4096, &lds[buf][4096 + tid * 8]); \
    } while (0)

    STAGE(0, 0);
    for (int t = 0; t < 32; ++t) {
        const int cur = t & 1;
        if (t < 31) {
            STAGE(cur ^ 1, t + 1);
            asm volatile("s_waitcnt vmcnt(2)" ::: "memory");
        } else {
            asm volatile("s_waitcnt vmcnt(0)" ::: "memory");
        }
        __builtin_amdgcn_s_barrier();

        f16x8 ah[2], al[2], bh, bl;
#pragma unroll
        for (int i = 0; i < 2; ++i) {
            int ao = ((wm * 2 + i) * 64 + lane) * 8;
            ah[i] = *reinterpret_cast<const f16x8*>(&lds[cur][ao]);
            al[i] = *reinterpret_cast<const f16x8*>(&lds[cur][2048 + ao]);
        }
        {
            int bo = (wn * 64 + lane) * 8;
            bh = *reinterpret_cast<const f16x8*>(&lds[cur][4096 + bo]);
            bl = *reinterpret_cast<const f16x8*>(&lds[cur][6144 + bo]);
        }
        __builtin_amdgcn_s_setprio(1);
#pragma unroll
        for (int i = 0; i < 2; ++i) {
            acc_h[i] = __builtin_amdgcn_mfma_f32_32x32x16_f16(ah[i], bh, acc_h[i], 0, 0, 0);
            acc_l[i] = __builtin_amdgcn_mfma_f32_32x32x16_f16(ah[i], bl, acc_l[i], 0, 0, 0);
            acc_l[i] = __builtin_amdgcn_mfma_f32_32x32x16_f16(al[i], bh, acc_l[i], 0, 0, 0);
        }
        __builtin_amdgcn_s_setprio(0);
        asm volatile("s_waitcnt lgkmcnt(0)" ::: "memory");
        __builtin_amdgcn_s_barrier();
    }
#undef STAGE

#pragma unroll
    for (int i = 0; i < 2; ++i) {
#pragma unroll
        for (int r = 0; r < 16; ++r) {
            int node = bx * 128 + wm * 64 + i * 32 + ((r & 3) + 8 * (r >> 2) + 4 * (lane >> 5));
            if (node < NNODES) {
                float w0 = W[(size_t)node * 513];
                float bt = beta[node];
                float z = acc_h[i][r] + acc_l[i][r] * 4.8828125e-4f;
                float s = bt * (z + w0);
                float p = 1.f / (1.f + expf(-s));
                PT[(size_t)node * B_ROWS + by * 128 + wn * 32 + (lane & 31)] = p;
            }
        }
    }
}

// ---------------------------------------------------------------------------
// Tree pass + fused colsum (unchanged from R11).
// ---------------------------------------------------------------------------
__global__ __launch_bounds__(256, 4)
void tree_pass(const float* __restrict__ PT,
               __hip_bfloat16* __restrict__ MU2,
               float* __restrict__ pval,          // [16][16384]
               int*   __restrict__ pidx,          // [16][16384]
               float* __restrict__ leafsum)       // [1024], pre-zeroed
{
    __shared__ float cs[32][257];
    __shared__ float ps[32][8];
    const int tid = threadIdx.x;
    const int rb = blockIdx.x & 63;
    const int g  = blockIdx.x >> 6;        // pair 0..15
    const int b  = rb * 256 + tid;

    const int c4 = 15 + g;
    const int n3 = (c4 - 1) >> 1;
    const int n2 = (n3 - 1) >> 1;
    const int n1 = (n2 - 1) >> 1;
    const float pc4 = PT[(size_t)c4 * B_ROWS + b];
    const float pn3 = PT[(size_t)n3 * B_ROWS + b];
    const float pn2 = PT[(size_t)n2 * B_ROWS + b];
    const float pn1 = PT[(size_t)n1 * B_ROWS + b];
    const float pn0 = PT[b];
    float pre = ((c4 & 1) ? pn3 : 1.f - pn3)
              * ((n3 & 1) ? pn2 : 1.f - pn2)
              * ((n2 & 1) ? pn1 : 1.f - pn1)
              * ((n1 & 1) ? pn0 : 1.f - pn0);
    float root[2] = { pre * pc4, pre * (1.f - pc4) };

    __align__(16) __hip_bfloat16 mbv[64];
    float bestv = -1.f; int besti = 0;
#pragma unroll
    for (int ss = 0; ss < 2; ++ss) {
        const int t = 2 * g + ss;
        float s[32];
#pragma unroll
        for (int u = 1; u < 32; ++u) {
            int lvl = 31 - __clz(u);
            int node = ((32 << lvl) - 1) + t * (1 << lvl) + (u - (1 << lvl));
            s[u] = PT[(size_t)node * B_ROWS + b];
        }
        float w[64];
        w[1] = root[ss];
#pragma unroll
        for (int u = 1; u < 32; ++u) {
            w[2 * u]     = w[u] * s[u];
            w[2 * u + 1] = w[u] * (1.f - s[u]);
        }
#pragma unroll
        for (int q = 0; q < 32; ++q) {
            float lv = w[32 + q];
            mbv[ss * 32 + q] = __float2bfloat16(lv);
            if (lv > bestv) { bestv = lv; besti = t * 32 + q; }
        }
        // fused colsum: LDS transpose reduce over the block's 256 rows
#pragma unroll
        for (int q = 0; q < 32; ++q) cs[q][tid] = w[32 + q];
        __syncthreads();
        {
            const int q = tid & 31, seg = tid >> 5;
            float sum = 0.f;
#pragma unroll
            for (int r = 0; r < 32; ++r) sum += cs[q][seg * 32 + r];
            ps[q][seg] = sum;
        }
        __syncthreads();
        if (tid < 32) {
            float tot = 0.f;
#pragma unroll
            for (int sg = 0; sg < 8; ++sg) tot += ps[tid][sg];
            atomicAdd(&leafsum[t * 32 + tid], tot);
        }
        __syncthreads();
    }
    {
        const int mb_ = b >> 7, mt_ = (b >> 5) & 3, lnlo = b & 31;
        const ulonglong2* src = reinterpret_cast<const ulonglong2*>(mbv);
#pragma unroll
        for (int c = 0; c < 4; ++c) {
            size_t base16 = (((size_t)mb_ * 64 + g * 4 + c) * 4 + mt_) * 64;
            *reinterpret_cast<ulonglong2*>(&MU2[(base16 + lnlo) * 8])      = src[c * 2];
            *reinterpret_cast<ulonglong2*>(&MU2[(base16 + 32 + lnlo) * 8]) = src[c * 2 + 1];
        }
    }
    pval[(size_t)g * B_ROWS + b] = bestv;
    pidx[(size_t)g * B_ROWS + b] = besti;
}

// ---------------------------------------------------------------------------
// tail: blocks 0..255 = GEMM2 (out1 = log(MU2 @ DT2));
//       blocks 256..511 = argmax over 16 partials + gather logdist rows;
//       block 512 = penalty from leafsum.
// All inputs produced by prior dispatches; no intra-dispatch deps.
// ---------------------------------------------------------------------------
__global__ __launch_bounds__(256)
void tail_kernel(const __hip_bfloat16* __restrict__ MU2,
                 const __hip_bfloat16* __restrict__ DT2,
                 float* __restrict__ out1,
                 const float* __restrict__ pval, const int* __restrict__ pidx,
                 const float* __restrict__ logdist, float* __restrict__ out0,
                 const float* __restrict__ leafsum, float* __restrict__ out_pen)
{
    __shared__ __hip_bfloat16 ldsA[2][2048];
    __shared__ __hip_bfloat16 ldsB[2][8192];
    __shared__ float M[2048];
    __shared__ double dred[256];
    __shared__ int sid[64];
    const int tid = threadIdx.x;

    if (blockIdx.x >= 512) {
        // ---- penalty ----
        for (int i = tid; i < 1024; i += 256) M[1024 + i] = leafsum[i];
        __syncthreads();
        for (int n = 512; n >= 1; n >>= 1) {
            for (int u = n + tid; u < 2 * n; u += 256) M[u] = M[2 * u] + M[2 * u + 1];
            __syncthreads();
        }
        double acc = 0.0;
        for (int u = 2 + tid; u < 2048; u += 256) {
            int lvl = 31 - __clz(u);
            float a = M[u] / (M[u >> 1] + EPSV);
            a = fminf(fmaxf(a, EPSV), 1.f - EPSV);
            float term = logf(a) + logf(1.f - a);
            acc -= ldexp((double)LAMDA * 0.5, 1 - lvl) * (double)term;
        }
        dred[tid] = acc;
        __syncthreads();
        for (int s = 128; s > 0; s >>= 1) {
            if (tid < s) dred[tid] += dred[tid + s];
            __syncthreads();
        }
        if (tid == 0) out_pen[0] = (float)dred[0];
        return;
    }
    if (blockIdx.x >= 256) {
        // ---- argmax + gather ----
        const int blk = blockIdx.x - 256;   // 256 blocks x 64 rows
        if (tid < 64) {
            int row = blk * 64 + tid;
            float bv = -1.f; int bi = 0;
            for (int g = 0; g < 16; ++g) {
                float v = pval[(size_t)g * B_ROWS + row];
                if (v > bv) { bv = v; bi = pidx[(size_t)g * B_ROWS + row]; }
            }
            sid[tid] = bi;
        }
        __syncthreads();
        for (int rr = 0; rr < 64; ++rr) {
            int id = sid[rr];
            out0[(size_t)(blk * 64 + rr) * ODIM + tid] = logdist[(size_t)id * ODIM + tid];
        }
        return;
    }
    // ---- GEMM2 ----
    const int lane = tid & 63;
    const int w = tid >> 6;
    const int blk = blockIdx.x;
    const int m0 = blk * 64;
    const int mb = blk >> 1;
    const int mtbase = (blk & 1) * 2;
    const int s_kcl = tid >> 7, s_mti = (tid >> 6) & 1, s_ln = tid & 63;

    f32x16v acc[2][2] = {};

#define STAGE2(buf, kc0) do { \
        size_t sa16 = (((size_t)mb * 64 + (kc0) + s_kcl) * 4 + mtbase + s_mti) * 64 + s_ln; \
        gload16b(MU2 + sa16 * 8, &ldsA[buf][tid * 8]); \
        gload16b(DT2 + ((size_t)(kc0) * 512 + tid) * 8,             &ldsB[buf][tid * 8]); \
        gload16b(DT2 + ((size_t)(kc0) * 512 + 256 + tid) * 8,       &ldsB[buf][2048 + tid * 8]); \
        gload16b(DT2 + ((size_t)((kc0) + 1) * 512 + tid) * 8,       &ldsB[buf][4096 + tid * 8]); \
        gload16b(DT2 + ((size_t)((kc0) + 1) * 512 + 256 + tid) * 8, &ldsB[buf][6144 + tid * 8]); \
    } while (0)

    STAGE2(0, 0);
    for (int it = 0; it < 32; ++it) {
        const int cur = it & 1;
        if (it + 1 < 32) {
            STAGE2(cur ^ 1, 2 * (it + 1));
            asm volatile("s_waitcnt vmcnt(5)" ::: "memory");
        } else {
            asm volatile("s_waitcnt vmcnt(0)" ::: "memory");
        }
        __builtin_amdgcn_s_barrier();
        bf16x8v a[2][2], bb[2][2];
#pragma unroll
        for (int kcl = 0; kcl < 2; ++kcl)
#pragma unroll
            for (int i = 0; i < 2; ++i) {
                a[kcl][i]  = *reinterpret_cast<const bf16x8v*>(&ldsA[cur][((kcl * 2 + i) * 64 + lane) * 8]);
                bb[kcl][i] = *reinterpret_cast<const bf16x8v*>(&ldsB[cur][((kcl * 8 + 2 * w + i) * 64 + lane) * 8]);
            }
        __builtin_amdgcn_s_setprio(1);
#pragma unroll
        for (int kcl = 0; kcl < 2; ++kcl)
#pragma unroll
            for (int i = 0; i < 2; ++i)
#pragma unroll
                for (int j = 0; j < 2; ++j)
                    acc[i][j] = __builtin_amdgcn_mfma_f32_32x32x16_bf16(a[kcl][i], bb[kcl][j], acc[i][j], 0, 0, 0);
        __builtin_amdgcn_s_setprio(0);
        asm volatile("s_waitcnt lgkmcnt(0)" ::: "memory");
        __builtin_amdgcn_s_barrier();
    }
#undef STAGE2
#pragma unroll
    for (int i = 0; i < 2; ++i)
#pragma unroll
        for (int j = 0; j < 2; ++j)
#pragma unroll
            for (int r = 0; r < 16; ++r) {
                int row = m0 + i * 32 + (r & 3) + 8 * (r >> 2) + 4 * (lane >> 5);
                int col = w * 64 + j * 32 + (lane & 31);
                out1[(size_t)row * ODIM + col] = logf(acc[i][j][r]);
            }
}

// ---------------------------------------------------------------------------
extern "C" void kernel_launch(void* const* d_in, const int* in_sizes, int n_in,
                              void* d_out, int out_size, void* d_ws, size_t ws_size,
                              hipStream_t stream)
{
    (void)in_sizes; (void)n_in; (void)out_size; (void)ws_size;
    const float* data  = (const float*)d_in[0];
    const float* W     = (const float*)d_in[1];
    const float* beta  = (const float*)d_in[2];
    const float* param = (const float*)d_in[3];
    float* out = (float*)d_out;

    char* ws = (char*)d_ws;
    size_t off = 0;
    float* PT = (float*)(ws + off);                   off += (size_t)NNODES * B_ROWS * 4;   // 67.04 MB
    char* X = ws + off;                               off += 2 * 1048576 + 2 * 16777216;    // 35.65 MB
    _Float16* Wh = (_Float16*)(X);
    _Float16* Wl = (_Float16*)(X + 1048576);
    _Float16* Dh = (_Float16*)(X + 2 * 1048576);
    _Float16* Dl = (_Float16*)(X + 2 * 1048576 + 16777216);
    __hip_bfloat16* MU2 = (__hip_bfloat16*)(X + 2 * 1048576);  // overlays Dh+Dl (33.55 MB)
    __hip_bfloat16* DT2 = (__hip_bfloat16*)(ws + off); off += (size_t)ODIM * NLEAF * 2;
    float* logdist = (float*)(ws + off);              off += (size_t)NLEAF * ODIM * 4;
    float* leafsum = (float*)(ws + off);              off += (size_t)NLEAF * 4;
    float* pval    = (float*)(ws + off);              off += (size_t)16 * B_ROWS * 4;
    int*   pidx    = (int*)(ws + off);                off += (size_t)16 * B_ROWS * 4;

    float* out_logpred = out;
    float* out_logout  = out + (size_t)B_ROWS * ODIM;
    float* out_pen     = out + 2 * (size_t)B_ROWS * ODIM;
    float* out_W       = out_pen + 1;

    prep_all<<<7429, 256, 0, stream>>>(data, W, param, Dh, Dl, Wh, Wl, out_W,
                                       logdist, DT2, leafsum);

    gemm1_mfma<<<1024, 512, 0, stream>>>(Wh, Wl, Dh, Dl, W, beta, PT);

    tree_pass<<<1024, 256, 0, stream>>>(PT, MU2, pval, pidx, leafsum);

    tail_kernel<<<513, 256, 0, stream>>>(MU2, DT2, out_logout,
                                         pval, pidx, logdist, out_logpred,
                                         leafsum, out_pen);
}